// Round 10
// baseline (104.094 us; speedup 1.0000x reference)
//
#include <hip/hip_runtime.h>
#include <hip/hip_bf16.h>

#define EPS 1e-8f
typedef unsigned short ushortT;
typedef __bf16 bf16x8 __attribute__((ext_vector_type(8)));
typedef float f32x4 __attribute__((ext_vector_type(4)));
union B8 { uint4 u; bf16x8 v; };

__device__ __forceinline__ float leaky(float x) { return x >= 0.f ? x : 0.1f * x; }

__device__ __forceinline__ ushortT f2bf(float v) {
    unsigned u = __float_as_uint(v);
    return (ushortT)((u + 0x7fffu + ((u >> 16) & 1u)) >> 16);
}

// Block-wide (256 thr) reduce of (s,q). Result valid on thread 0.
__device__ __forceinline__ void block_reduce2(float& s, float& q, float* red) {
    __syncthreads();
    #pragma unroll
    for (int off = 32; off > 0; off >>= 1) {
        s += __shfl_down(s, off, 64);
        q += __shfl_down(q, off, 64);
    }
    const int wid = threadIdx.x >> 6, lane = threadIdx.x & 63;
    if (lane == 0) { red[wid] = s; red[4 + wid] = q; }
    __syncthreads();
    if (threadIdx.x == 0) {
        s = red[0] + red[1] + red[2] + red[3];
        q = red[4] + red[5] + red[6] + red[7];
    }
}

__device__ __forceinline__ void stats_from_partials(const float* __restrict__ partials,
                                                    int n, float nrm,
                                                    float* red, float* stat) {
    float s = 0.f, q = 0.f;
    if ((int)threadIdx.x < n) {
        s = partials[threadIdx.x * 2];
        q = partials[threadIdx.x * 2 + 1];
    }
    block_reduce2(s, q, red);
    if (threadIdx.x == 0) {
        float mean = s * nrm;
        float var  = fmaxf(q * nrm - mean * mean, 0.f);
        stat[0] = mean;
        stat[1] = rsqrtf(var + EPS);
    }
    __syncthreads();
}

// KA: blocks x<63: t-tile of 32, ALL 128 p. Inline a (feature read 1x),
// maskmix (mask read 1x, float4), LDS transpose, dT[t][p] float4 writes, stats0.
// blocks x>=63: bf16 weight prep (288 chunks of 1024 floats) + counter zeroing.
__global__ void ka(const float* __restrict__ feature, const float* __restrict__ mask,
                   const float* __restrict__ w2d, const float* __restrict__ b2d,
                   const float* __restrict__ w1, const float* __restrict__ w2,
                   ushortT* __restrict__ w1b, ushortT* __restrict__ w2b,
                   float* __restrict__ dT, float* __restrict__ p0out,
                   int* __restrict__ cnt) {
    if (blockIdx.x >= 63) {
        if (blockIdx.x == 63 && blockIdx.y == 0 && threadIdx.x < 16)
            cnt[threadIdx.x] = 0;
        int p = (blockIdx.x - 63) * 4 + blockIdx.y;
        int base = (p < 96 ? p : p - 96) * 1024 + threadIdx.x * 4;
        const float* src = (p < 96) ? (w1 + base) : (w2 + base);
        ushortT* dst = (p < 96) ? (w1b + base) : (w2b + base);
        float4 v = *(const float4*)src;
        ushort4 o;
        o.x = f2bf(v.x); o.y = f2bf(v.y); o.z = f2bf(v.z); o.w = f2bf(v.w);
        *(ushort4*)dst = o;
        return;
    }
    __shared__ float4 apart[2][32][8];
    __shared__ float4 a0s4[8], a1s4[8];
    __shared__ float Xt[32][132];
    __shared__ float red[8];
    const int b = blockIdx.y;
    const int t0 = blockIdx.x * 32;
    const int tq = threadIdx.x & 7;        // float4 t-index: t = t0 + tq*4
    const int hi = threadIdx.x >> 3;       // 0..31

    // phase 1: a-partials. thread (tq, fg=hi): 4 f's, float4 over t.
    {
        const int tbase = t0 + tq * 4;
        float4 s0 = {0.f, 0.f, 0.f, 0.f}, s1 = s0;
        if (tbase + 3 < 2000) {
            const float* fb = feature + ((size_t)b * 128 + hi * 4) * 2000 + tbase;
            float4 wa = *(const float4*)(w2d + hi * 4);
            float4 wc = *(const float4*)(w2d + 128 + hi * 4);
            float wav[4] = {wa.x, wa.y, wa.z, wa.w};
            float wcv[4] = {wc.x, wc.y, wc.z, wc.w};
            #pragma unroll
            for (int i = 0; i < 4; i++) {
                float4 fv = *(const float4*)(fb + (size_t)i * 2000);
                s0.x = fmaf(wav[i], fv.x, s0.x); s0.y = fmaf(wav[i], fv.y, s0.y);
                s0.z = fmaf(wav[i], fv.z, s0.z); s0.w = fmaf(wav[i], fv.w, s0.w);
                s1.x = fmaf(wcv[i], fv.x, s1.x); s1.y = fmaf(wcv[i], fv.y, s1.y);
                s1.z = fmaf(wcv[i], fv.z, s1.z); s1.w = fmaf(wcv[i], fv.w, s1.w);
            }
        }
        apart[0][hi][tq] = s0;
        apart[1][hi][tq] = s1;
    }
    __syncthreads();
    if (threadIdx.x < 16) {
        int c = threadIdx.x >> 3, tqq = threadIdx.x & 7;
        float4 s = {0.f, 0.f, 0.f, 0.f};
        #pragma unroll
        for (int i = 0; i < 32; i++) {
            float4 v = apart[c][i][tqq];
            s.x += v.x; s.y += v.y; s.z += v.z; s.w += v.w;
        }
        (c ? a1s4 : a0s4)[tqq] = s;
    }
    __syncthreads();

    // phase 2: maskmix over 4 p rows per thread (p = hi*4..+4), float4 over t.
    const float bb = b2d[0];
    float s = 0.f, q = 0.f;
    {
        const int tbase = t0 + tq * 4;
        if (tbase + 3 < 2000) {
            float4 a0 = a0s4[tq], a1 = a1s4[tq];
            const float* m0p = mask + ((size_t)(b * 2 + 0) * 128 + hi * 4) * 2000 + tbase;
            const float* m1p = mask + ((size_t)(b * 2 + 1) * 128 + hi * 4) * 2000 + tbase;
            #pragma unroll
            for (int j = 0; j < 4; j++) {
                int p = hi * 4 + j;
                float4 m0 = *(const float4*)(m0p + (size_t)j * 2000);
                float4 m1 = *(const float4*)(m1p + (size_t)j * 2000);
                float v0 = fmaf(a0.x, m0.x, a1.x * m1.x) + bb;
                float v1 = fmaf(a0.y, m0.y, a1.y * m1.y) + bb;
                float v2 = fmaf(a0.z, m0.z, a1.z * m1.z) + bb;
                float v3 = fmaf(a0.w, m0.w, a1.w * m1.w) + bb;
                Xt[tq * 4 + 0][p] = v0;
                Xt[tq * 4 + 1][p] = v1;
                Xt[tq * 4 + 2][p] = v2;
                Xt[tq * 4 + 3][p] = v3;
                s += v0 + v1 + v2 + v3;
                q = fmaf(v0, v0, q); q = fmaf(v1, v1, q);
                q = fmaf(v2, v2, q); q = fmaf(v3, v3, q);
            }
        }
    }
    block_reduce2(s, q, red);
    if (threadIdx.x == 0) {
        p0out[(b * 128 + blockIdx.x) * 2]     = s;
        p0out[(b * 128 + blockIdx.x) * 2 + 1] = q;
    }
    // phase 3: dT[t][p] float4 writes (Xt synced inside block_reduce2).
    {
        const int tw = threadIdx.x >> 3;           // 0..31
        if (t0 + tw < 2000) {
            float* drow = dT + (size_t)b * 256000 + (size_t)(t0 + tw) * 128;
            #pragma unroll
            for (int jj = 0; jj < 4; jj++) {
                int p4 = (threadIdx.x & 7) + jj * 8;   // 0..31
                float4 v = *(const float4*)&Xt[tw][p4 * 4];
                *(float4*)(drow + p4 * 4) = v;
            }
        }
    }
}

// Conv: Y[o,t] = bias[o] + sum_k W[o,k]*X[k,t], k=f*3+kk,
// X[k,t]=leaky(LN(xT[2t-1+kk][f])). Input TRANSPOSED [ti][CIN], float4 staging.
// 16x16x32 bf16 MFMA. MPB out-rows/block, NT t-cols. grid (tiles*(256/MPB), 4).
// TAIL: last-8-finishers per batch execute the final 1x1 conv head (kd).
template <int CIN, int TIN, int TOUT, int NT, int MPB, bool PERCH, bool TOUT_TRANS,
          bool TAIL>
__launch_bounds__(256, 2)
__global__ void kconv(const float* __restrict__ xT, const float* __restrict__ pin,
                      int npin, float nrm,
                      const float* __restrict__ gam, const float* __restrict__ bet,
                      const ushortT* __restrict__ wb, const float* __restrict__ bias,
                      float* __restrict__ yout, float* __restrict__ pout,
                      const float* __restrict__ g2t, const float* __restrict__ bb2t,
                      const float* __restrict__ w3t, const float* __restrict__ b3t,
                      float* __restrict__ outp, int* __restrict__ cnt) {
    constexpr int K = CIN * 3;
    constexpr int ROWB = K * 2;              // LDS bytes per t-row (bf16)
    constexpr int NF = NT / 16;
    constexpr int MSC = 256 / MPB;
    constexpr int MF = MPB / 64;
    constexpr int LPR = CIN / 4;             // float4 lanes per staging row
    constexpr int RPP = 256 / LPR;           // staging rows per pass
    constexpr int NPASS = (2 * NT) / RPP + 1;
    __shared__ char Xs[NT * ROWB];
    __shared__ float red[8];
    __shared__ float stat[2];
    __shared__ int oldv;

    const int b = blockIdx.y;
    const int ms = blockIdx.x % MSC;
    const int tile = blockIdx.x / MSC;
    const int t0 = tile * NT;
    const int lane = threadIdx.x & 63;
    const int wv = threadIdx.x >> 6;

    stats_from_partials(pin + b * 256, npin, nrm, red, stat);
    const float mean = stat[0], inv = stat[1];

    // ---- staging ----
    const int rl = threadIdx.x / LPR;
    const int f0 = (threadIdx.x % LPR) * 4;
    float gg[4], bv[4];
    if (PERCH) {
        float4 g4 = *(const float4*)(gam + f0);
        float4 b4 = *(const float4*)(bet + f0);
        gg[0] = g4.x; gg[1] = g4.y; gg[2] = g4.z; gg[3] = g4.w;
        bv[0] = b4.x; bv[1] = b4.y; bv[2] = b4.z; bv[3] = b4.w;
    } else {
        gg[0] = gg[1] = gg[2] = gg[3] = gam[0];
        bv[0] = bv[1] = bv[2] = bv[3] = bet[0];
    }
    const int base_ti = 2 * t0 - 1;
    #pragma unroll
    for (int pass = 0; pass < NPASS; pass++) {
        int c = pass * RPP + rl;
        if (c > 2 * NT) continue;
        int ti = base_ti + c;
        float4 x4 = {0.f, 0.f, 0.f, 0.f};
        if (ti >= 0 && ti < TIN)
            x4 = *(const float4*)(xT + ((size_t)b * TIN + ti) * CIN + f0);
        float xv[4] = {x4.x, x4.y, x4.z, x4.w};
        ushortT h[4];
        #pragma unroll
        for (int j = 0; j < 4; j++)
            h[j] = f2bf(leaky(fmaf(gg[j] * inv, xv[j] - mean, bv[j])));
        if (c & 1) {                         // kk=1 at tt=(c-1)/2
            int tt = (c - 1) >> 1;
            int ad = tt * ROWB, sw = (tt & 7) << 4;
            #pragma unroll
            for (int j = 0; j < 4; j++)
                *(ushortT*)(Xs + ((ad + ((f0 + j) * 3 + 1) * 2) ^ sw)) = h[j];
        } else {                             // kk=0 at tt=c/2 ; kk=2 at tt=c/2-1
            int tt = c >> 1;
            if (tt < NT) {
                int ad = tt * ROWB, sw = (tt & 7) << 4;
                #pragma unroll
                for (int j = 0; j < 4; j++)
                    *(ushortT*)(Xs + ((ad + (f0 + j) * 6) ^ sw)) = h[j];
            }
            if (tt >= 1) {
                int ad = (tt - 1) * ROWB, sw = ((tt - 1) & 7) << 4;
                #pragma unroll
                for (int j = 0; j < 4; j++)
                    *(ushortT*)(Xs + ((ad + (f0 + j) * 6 + 4) ^ sw)) = h[j];
            }
        }
    }
    __syncthreads();

    // ---- MFMA ----
    const int obase = ms * MPB + wv * (MPB / 4);
    const int kgrp = (lane >> 4) * 8;
    const int mrow = lane & 15;
    f32x4 acc[MF][NF];
    #pragma unroll
    for (int mf = 0; mf < MF; mf++)
        #pragma unroll
        for (int nf = 0; nf < NF; nf++) acc[mf][nf] = (f32x4){0.f, 0.f, 0.f, 0.f};
    #pragma unroll 2
    for (int ks = 0; ks < K / 32; ks++) {
        int kb = ks * 32 + kgrp;
        B8 afr[MF];
        #pragma unroll
        for (int mf = 0; mf < MF; mf++)
            afr[mf].u = *(const uint4*)(wb + (size_t)(obase + mf * 16 + mrow) * K + kb);
        #pragma unroll
        for (int nf = 0; nf < NF; nf++) {
            int tt = nf * 16 + mrow;
            int ad = (tt * ROWB + kb * 2) ^ ((tt & 7) << 4);
            B8 bfr; bfr.u = *(const uint4*)(Xs + ad);
            #pragma unroll
            for (int mf = 0; mf < MF; mf++)
                acc[mf][nf] = __builtin_amdgcn_mfma_f32_16x16x32_bf16(
                    afr[mf].v, bfr.v, acc[mf][nf], 0, 0, 0);
        }
    }

    // ---- epilogue ----
    float s = 0.f, q = 0.f;
    #pragma unroll
    for (int mf = 0; mf < MF; mf++) {
        const int o0 = obase + mf * 16 + (lane >> 4) * 4;
        if (TOUT_TRANS) {
            float4 b4 = *(const float4*)(bias + o0);
            float bi[4] = {b4.x, b4.y, b4.z, b4.w};
            #pragma unroll
            for (int nf = 0; nf < NF; nf++) {
                int t = t0 + nf * 16 + mrow;
                if (t < TOUT) {
                    float v0 = acc[mf][nf][0] + bi[0], v1 = acc[mf][nf][1] + bi[1];
                    float v2 = acc[mf][nf][2] + bi[2], v3 = acc[mf][nf][3] + bi[3];
                    float4 v = {v0, v1, v2, v3};
                    *(float4*)(yout + ((size_t)b * TOUT + t) * 256 + o0) = v;
                    s += v0 + v1 + v2 + v3;
                    q = fmaf(v0, v0, q); q = fmaf(v1, v1, q);
                    q = fmaf(v2, v2, q); q = fmaf(v3, v3, q);
                }
            }
        } else {
            #pragma unroll
            for (int nf = 0; nf < NF; nf++) {
                int t = t0 + nf * 16 + mrow;
                if (t < TOUT) {
                    #pragma unroll
                    for (int r = 0; r < 4; r++) {
                        float v = acc[mf][nf][r] + bias[o0 + r];
                        yout[((size_t)b * 256 + o0 + r) * TOUT + t] = v;
                        s += v; q = fmaf(v, v, q);
                    }
                }
            }
        }
    }
    block_reduce2(s, q, red);
    if (threadIdx.x == 0) {
        int bi = b * 128 + tile * MSC + ms;
        pout[bi * 2]     = s;
        pout[bi * 2 + 1] = q;
    }

    // ---- TAIL: last-8-finishers per batch run the 1x1 head over 64-t chunks ----
    if (TAIL) {
        constexpr int NPROD = 128;           // producer blocks per batch
        __threadfence();                     // release: y2 + partials visible
        if (threadIdx.x == 0)
            oldv = __hip_atomic_fetch_add(&cnt[b], 1, __ATOMIC_RELAXED,
                                          __HIP_MEMORY_SCOPE_AGENT);
        __syncthreads();
        const int old = oldv;
        if (old >= NPROD - 8) {
            const int part_id = old - (NPROD - 8);   // 0..7
            if (threadIdx.x == 0) {
                while (__hip_atomic_load(&cnt[b], __ATOMIC_RELAXED,
                                         __HIP_MEMORY_SCOPE_AGENT) < NPROD)
                    __builtin_amdgcn_s_sleep(2);
            }
            __syncthreads();
            __threadfence();                 // acquire: see all producers' writes
            stats_from_partials(pout + b * 256, NPROD, 1.f / (256.f * TOUT),
                                red, stat);
            const float mean2 = stat[0], inv2 = stat[1];
            const int tl = threadIdx.x & 63, fg = threadIdx.x >> 6;
            const int t = part_id * 64 + tl;
            float accv = 0.f;
            if (t < TOUT) {
                const float* yb = yout + ((size_t)b * 256 + fg * 64) * TOUT + t;
                #pragma unroll 8
                for (int i = 0; i < 64; i++) {
                    int o = fg * 64 + i;
                    float raw = yb[(size_t)i * TOUT];
                    float xv = leaky(fmaf(g2t[o] * inv2, raw - mean2, bb2t[o]));
                    accv = fmaf(w3t[o], xv, accv);
                }
            }
            float* part = (float*)Xs;        // reuse LDS: [4][64]
            part[fg * 64 + tl] = accv;
            __syncthreads();
            if (fg == 0 && t < TOUT)
                outp[b * TOUT + t] = b3t[0] + part[0 * 64 + tl] + part[1 * 64 + tl]
                                   + part[2 * 64 + tl] + part[3 * 64 + tl];
        }
    }
}

extern "C" void kernel_launch(void* const* d_in, const int* in_sizes, int n_in,
                              void* d_out, int out_size, void* d_ws, size_t ws_size,
                              hipStream_t stream) {
    const float* feature = (const float*)d_in[0];
    const float* mask    = (const float*)d_in[1];
    const float* w2d     = (const float*)d_in[2];
    const float* b2d     = (const float*)d_in[3];
    const float* g2d     = (const float*)d_in[4];
    const float* be2d    = (const float*)d_in[5];
    const float* w1      = (const float*)d_in[6];
    const float* b1      = (const float*)d_in[7];
    const float* g1      = (const float*)d_in[8];
    const float* bb1     = (const float*)d_in[9];
    const float* w2      = (const float*)d_in[10];
    const float* b2      = (const float*)d_in[11];
    const float* g2      = (const float*)d_in[12];
    const float* bb2     = (const float*)d_in[13];
    const float* w3      = (const float*)d_in[14];
    const float* b3      = (const float*)d_in[15];
    float* out = (float*)d_out;

    float* ws = (float*)d_ws;
    float* p0  = ws;                      // 1024
    float* p1  = ws + 1024;               // 1024
    float* p2  = ws + 2048;               // 1024
    int*   cnt = (int*)(ws + 3072);       // 16 ints
    float* dT  = ws + 3088;               // [b][2000][128] = 1,024,000
    float* y1T = dT + 1024000;            // [b][1000][256] = 1,024,000
    float* y2  = y1T + 1024000;           // [b][256][500]  = 512,000
    ushortT* w1b = (ushortT*)(y2 + 512000);   // 98,304 ushorts
    ushortT* w2b = w1b + 98304;               // 196,608 ushorts

    // A: inline-a + maskmix + transpose + stats0 (+ weight prep, counter zero).
    ka<<<dim3(63 + 72, 4), 256, 0, stream>>>(feature, mask, w2d, b2d,
                                             w1, w2, w1b, w2b, dT, p0, cnt);
    // B: conv1 128->256, T 2000->1000, NT=16, MPB=128, 504 blocks, y1T[t][o].
    kconv<128, 2000, 1000, 16, 128, false, true, false>
        <<<dim3(126, 4), 256, 0, stream>>>(
        dT, p0, 63, 1.f / 256000.f, g2d, be2d, w1b, b1, y1T, p1,
        nullptr, nullptr, nullptr, nullptr, nullptr, cnt);
    // C: conv2 256->256, T 1000->500, NT=16, MPB=64, 512 blocks, y2[o][t],
    //    + fused kd tail (last 8 finishers per batch).
    kconv<256, 1000, 500, 16, 64, true, false, true>
        <<<dim3(128, 4), 256, 0, stream>>>(
        y1T, p1, 126, 1.f / 256000.f, g1, bb1, w2b, b2, y2, p2,
        g2, bb2, w3, b3, out, cnt);
}

// Round 11
// 40.305 us; speedup vs baseline: 2.5826x; 2.5826x over previous
//
#include <hip/hip_runtime.h>
#include <hip/hip_bf16.h>

#define EPS 1e-8f
typedef unsigned short ushortT;
typedef __bf16 bf16x8 __attribute__((ext_vector_type(8)));
typedef float f32x4 __attribute__((ext_vector_type(4)));
union B8 { uint4 u; bf16x8 v; };

__device__ __forceinline__ float leaky(float x) { return x >= 0.f ? x : 0.1f * x; }

__device__ __forceinline__ ushortT f2bf(float v) {
    unsigned u = __float_as_uint(v);
    return (ushortT)((u + 0x7fffu + ((u >> 16) & 1u)) >> 16);
}
__device__ __forceinline__ float bf2f(ushortT h) {
    return __uint_as_float(((unsigned)h) << 16);
}

// Block-wide (256 thr) reduce of (s,q). Result valid on thread 0.
__device__ __forceinline__ void block_reduce2(float& s, float& q, float* red) {
    __syncthreads();
    #pragma unroll
    for (int off = 32; off > 0; off >>= 1) {
        s += __shfl_down(s, off, 64);
        q += __shfl_down(q, off, 64);
    }
    const int wid = threadIdx.x >> 6, lane = threadIdx.x & 63;
    if (lane == 0) { red[wid] = s; red[4 + wid] = q; }
    __syncthreads();
    if (threadIdx.x == 0) {
        s = red[0] + red[1] + red[2] + red[3];
        q = red[4] + red[5] + red[6] + red[7];
    }
}

__device__ __forceinline__ void stats_from_partials(const float* __restrict__ partials,
                                                    int n, float nrm,
                                                    float* red, float* stat) {
    float s = 0.f, q = 0.f;
    if ((int)threadIdx.x < n) {
        s = partials[threadIdx.x * 2];
        q = partials[threadIdx.x * 2 + 1];
    }
    block_reduce2(s, q, red);
    if (threadIdx.x == 0) {
        float mean = s * nrm;
        float var  = fmaxf(q * nrm - mean * mean, 0.f);
        stat[0] = mean;
        stat[1] = rsqrtf(var + EPS);
    }
    __syncthreads();
}

// KA: blocks x<63: t-tile of 32, ALL 128 p. Inline a (feature read 1x),
// maskmix (mask read 1x, float4), LDS transpose, dT[t][p] bf16 writes, stats0.
// blocks x>=63: bf16 weight prep (288 chunks of 1024 floats).
__global__ void ka(const float* __restrict__ feature, const float* __restrict__ mask,
                   const float* __restrict__ w2d, const float* __restrict__ b2d,
                   const float* __restrict__ w1, const float* __restrict__ w2,
                   ushortT* __restrict__ w1b, ushortT* __restrict__ w2b,
                   ushortT* __restrict__ dT, float* __restrict__ p0out) {
    if (blockIdx.x >= 63) {
        int p = (blockIdx.x - 63) * 4 + blockIdx.y;
        int base = (p < 96 ? p : p - 96) * 1024 + threadIdx.x * 4;
        const float* src = (p < 96) ? (w1 + base) : (w2 + base);
        ushortT* dst = (p < 96) ? (w1b + base) : (w2b + base);
        float4 v = *(const float4*)src;
        ushort4 o;
        o.x = f2bf(v.x); o.y = f2bf(v.y); o.z = f2bf(v.z); o.w = f2bf(v.w);
        *(ushort4*)dst = o;
        return;
    }
    __shared__ float4 apart[2][32][8];
    __shared__ float4 a0s4[8], a1s4[8];
    __shared__ float Xt[32][132];
    __shared__ float red[8];
    const int b = blockIdx.y;
    const int t0 = blockIdx.x * 32;
    const int tq = threadIdx.x & 7;        // float4 t-index: t = t0 + tq*4
    const int hi = threadIdx.x >> 3;       // 0..31

    // phase 1: a-partials. thread (tq, hi): 4 f's, float4 over t.
    {
        const int tbase = t0 + tq * 4;
        float4 s0 = {0.f, 0.f, 0.f, 0.f}, s1 = s0;
        if (tbase + 3 < 2000) {
            const float* fb = feature + ((size_t)b * 128 + hi * 4) * 2000 + tbase;
            float4 wa = *(const float4*)(w2d + hi * 4);
            float4 wc = *(const float4*)(w2d + 128 + hi * 4);
            float wav[4] = {wa.x, wa.y, wa.z, wa.w};
            float wcv[4] = {wc.x, wc.y, wc.z, wc.w};
            #pragma unroll
            for (int i = 0; i < 4; i++) {
                float4 fv = *(const float4*)(fb + (size_t)i * 2000);
                s0.x = fmaf(wav[i], fv.x, s0.x); s0.y = fmaf(wav[i], fv.y, s0.y);
                s0.z = fmaf(wav[i], fv.z, s0.z); s0.w = fmaf(wav[i], fv.w, s0.w);
                s1.x = fmaf(wcv[i], fv.x, s1.x); s1.y = fmaf(wcv[i], fv.y, s1.y);
                s1.z = fmaf(wcv[i], fv.z, s1.z); s1.w = fmaf(wcv[i], fv.w, s1.w);
            }
        }
        apart[0][hi][tq] = s0;
        apart[1][hi][tq] = s1;
    }
    __syncthreads();
    if (threadIdx.x < 16) {
        int c = threadIdx.x >> 3, tqq = threadIdx.x & 7;
        float4 s = {0.f, 0.f, 0.f, 0.f};
        #pragma unroll
        for (int i = 0; i < 32; i++) {
            float4 v = apart[c][i][tqq];
            s.x += v.x; s.y += v.y; s.z += v.z; s.w += v.w;
        }
        (c ? a1s4 : a0s4)[tqq] = s;
    }
    __syncthreads();

    // phase 2: maskmix over 4 p rows per thread (p = hi*4..+4), float4 over t.
    const float bb = b2d[0];
    float s = 0.f, q = 0.f;
    {
        const int tbase = t0 + tq * 4;
        if (tbase + 3 < 2000) {
            float4 a0 = a0s4[tq], a1 = a1s4[tq];
            const float* m0p = mask + ((size_t)(b * 2 + 0) * 128 + hi * 4) * 2000 + tbase;
            const float* m1p = mask + ((size_t)(b * 2 + 1) * 128 + hi * 4) * 2000 + tbase;
            #pragma unroll
            for (int j = 0; j < 4; j++) {
                int p = hi * 4 + j;
                float4 m0 = *(const float4*)(m0p + (size_t)j * 2000);
                float4 m1 = *(const float4*)(m1p + (size_t)j * 2000);
                float v0 = fmaf(a0.x, m0.x, a1.x * m1.x) + bb;
                float v1 = fmaf(a0.y, m0.y, a1.y * m1.y) + bb;
                float v2 = fmaf(a0.z, m0.z, a1.z * m1.z) + bb;
                float v3 = fmaf(a0.w, m0.w, a1.w * m1.w) + bb;
                Xt[tq * 4 + 0][p] = v0;
                Xt[tq * 4 + 1][p] = v1;
                Xt[tq * 4 + 2][p] = v2;
                Xt[tq * 4 + 3][p] = v3;
                s += v0 + v1 + v2 + v3;
                q = fmaf(v0, v0, q); q = fmaf(v1, v1, q);
                q = fmaf(v2, v2, q); q = fmaf(v3, v3, q);
            }
        }
    }
    block_reduce2(s, q, red);
    if (threadIdx.x == 0) {
        p0out[(b * 128 + blockIdx.x) * 2]     = s;
        p0out[(b * 128 + blockIdx.x) * 2 + 1] = q;
    }
    // phase 3: dT[t][p] bf16 writes (Xt synced inside block_reduce2).
    {
        const int tw = threadIdx.x >> 3;           // 0..31
        if (t0 + tw < 2000) {
            ushortT* drow = dT + (size_t)b * 256000 + (size_t)(t0 + tw) * 128;
            #pragma unroll
            for (int jj = 0; jj < 4; jj++) {
                int p4 = (threadIdx.x & 7) + jj * 8;   // 0..31
                float4 v = *(const float4*)&Xt[tw][p4 * 4];
                ushort4 h;
                h.x = f2bf(v.x); h.y = f2bf(v.y); h.z = f2bf(v.z); h.w = f2bf(v.w);
                *(ushort4*)(drow + p4 * 4) = h;
            }
        }
    }
}

// Conv: Y[o,t] = bias[o] + sum_k W[o,k]*X[k,t], k=f*3+kk,
// X[k,t]=leaky(LN(xT[2t-1+kk][f])). Input TRANSPOSED [ti][CIN]; XBF: bf16 input.
// Staging loads PREFETCHED into registers before the stats reduction.
// 16x16x32 bf16 MFMA. MPB out-rows/block, NT t-cols. grid (tiles*(256/MPB), 4).
template <int CIN, int TIN, int TOUT, int NT, int MPB, bool PERCH, bool TOUT_TRANS,
          bool XBF>
__launch_bounds__(256, 2)
__global__ void kconv(const void* __restrict__ xTv, const float* __restrict__ pin,
                      int npin, float nrm,
                      const float* __restrict__ gam, const float* __restrict__ bet,
                      const ushortT* __restrict__ wb, const float* __restrict__ bias,
                      float* __restrict__ yout, float* __restrict__ pout) {
    constexpr int K = CIN * 3;
    constexpr int ROWB = K * 2;              // LDS bytes per t-row (bf16)
    constexpr int NF = NT / 16;
    constexpr int MSC = 256 / MPB;
    constexpr int MF = MPB / 64;
    constexpr int LPR = CIN / 4;             // 4-elem lanes per staging row
    constexpr int RPP = 256 / LPR;           // staging rows per pass
    constexpr int NPASS = (2 * NT) / RPP + 1;
    __shared__ char Xs[NT * ROWB];
    __shared__ float red[8];
    __shared__ float stat[2];

    const int b = blockIdx.y;
    const int ms = blockIdx.x % MSC;
    const int tile = blockIdx.x / MSC;
    const int t0 = tile * NT;
    const int lane = threadIdx.x & 63;
    const int wv = threadIdx.x >> 6;

    // ---- prefetch staging rows into registers (independent of stats) ----
    const int rl = threadIdx.x / LPR;
    const int f0 = (threadIdx.x % LPR) * 4;
    const int base_ti = 2 * t0 - 1;
    float xreg[NPASS][4];
    #pragma unroll
    for (int pass = 0; pass < NPASS; pass++) {
        int c = pass * RPP + rl;
        int ti = base_ti + c;
        xreg[pass][0] = xreg[pass][1] = xreg[pass][2] = xreg[pass][3] = 0.f;
        if (c <= 2 * NT && ti >= 0 && ti < TIN) {
            if (XBF) {
                ushort4 u = *(const ushort4*)((const ushortT*)xTv
                                + ((size_t)b * TIN + ti) * CIN + f0);
                xreg[pass][0] = bf2f(u.x); xreg[pass][1] = bf2f(u.y);
                xreg[pass][2] = bf2f(u.z); xreg[pass][3] = bf2f(u.w);
            } else {
                float4 x4 = *(const float4*)((const float*)xTv
                                + ((size_t)b * TIN + ti) * CIN + f0);
                xreg[pass][0] = x4.x; xreg[pass][1] = x4.y;
                xreg[pass][2] = x4.z; xreg[pass][3] = x4.w;
            }
        }
    }

    stats_from_partials(pin + b * 256, npin, nrm, red, stat);
    const float mean = stat[0], inv = stat[1];

    float gg[4], bv[4];
    if (PERCH) {
        float4 g4 = *(const float4*)(gam + f0);
        float4 b4 = *(const float4*)(bet + f0);
        gg[0] = g4.x; gg[1] = g4.y; gg[2] = g4.z; gg[3] = g4.w;
        bv[0] = b4.x; bv[1] = b4.y; bv[2] = b4.z; bv[3] = b4.w;
    } else {
        gg[0] = gg[1] = gg[2] = gg[3] = gam[0];
        bv[0] = bv[1] = bv[2] = bv[3] = bet[0];
    }

    // ---- LN + pack to LDS ----
    #pragma unroll
    for (int pass = 0; pass < NPASS; pass++) {
        int c = pass * RPP + rl;
        if (c > 2 * NT) continue;
        ushortT h[4];
        #pragma unroll
        for (int j = 0; j < 4; j++)
            h[j] = f2bf(leaky(fmaf(gg[j] * inv, xreg[pass][j] - mean, bv[j])));
        if (c & 1) {                         // kk=1 at tt=(c-1)/2
            int tt = (c - 1) >> 1;
            int ad = tt * ROWB, sw = (tt & 7) << 4;
            #pragma unroll
            for (int j = 0; j < 4; j++)
                *(ushortT*)(Xs + ((ad + ((f0 + j) * 3 + 1) * 2) ^ sw)) = h[j];
        } else {                             // kk=0 at tt=c/2 ; kk=2 at tt=c/2-1
            int tt = c >> 1;
            if (tt < NT) {
                int ad = tt * ROWB, sw = (tt & 7) << 4;
                #pragma unroll
                for (int j = 0; j < 4; j++)
                    *(ushortT*)(Xs + ((ad + (f0 + j) * 6) ^ sw)) = h[j];
            }
            if (tt >= 1) {
                int ad = (tt - 1) * ROWB, sw = ((tt - 1) & 7) << 4;
                #pragma unroll
                for (int j = 0; j < 4; j++)
                    *(ushortT*)(Xs + ((ad + (f0 + j) * 6 + 4) ^ sw)) = h[j];
            }
        }
    }
    __syncthreads();

    // ---- MFMA ----
    const int obase = ms * MPB + wv * (MPB / 4);
    const int kgrp = (lane >> 4) * 8;
    const int mrow = lane & 15;
    f32x4 acc[MF][NF];
    #pragma unroll
    for (int mf = 0; mf < MF; mf++)
        #pragma unroll
        for (int nf = 0; nf < NF; nf++) acc[mf][nf] = (f32x4){0.f, 0.f, 0.f, 0.f};
    #pragma unroll 2
    for (int ks = 0; ks < K / 32; ks++) {
        int kb = ks * 32 + kgrp;
        B8 afr[MF];
        #pragma unroll
        for (int mf = 0; mf < MF; mf++)
            afr[mf].u = *(const uint4*)(wb + (size_t)(obase + mf * 16 + mrow) * K + kb);
        #pragma unroll
        for (int nf = 0; nf < NF; nf++) {
            int tt = nf * 16 + mrow;
            int ad = (tt * ROWB + kb * 2) ^ ((tt & 7) << 4);
            B8 bfr; bfr.u = *(const uint4*)(Xs + ad);
            #pragma unroll
            for (int mf = 0; mf < MF; mf++)
                acc[mf][nf] = __builtin_amdgcn_mfma_f32_16x16x32_bf16(
                    afr[mf].v, bfr.v, acc[mf][nf], 0, 0, 0);
        }
    }

    // ---- epilogue ----
    float s = 0.f, q = 0.f;
    #pragma unroll
    for (int mf = 0; mf < MF; mf++) {
        const int o0 = obase + mf * 16 + (lane >> 4) * 4;
        if (TOUT_TRANS) {
            float4 b4 = *(const float4*)(bias + o0);
            float bi[4] = {b4.x, b4.y, b4.z, b4.w};
            #pragma unroll
            for (int nf = 0; nf < NF; nf++) {
                int t = t0 + nf * 16 + mrow;
                if (t < TOUT) {
                    float v0 = acc[mf][nf][0] + bi[0], v1 = acc[mf][nf][1] + bi[1];
                    float v2 = acc[mf][nf][2] + bi[2], v3 = acc[mf][nf][3] + bi[3];
                    float4 v = {v0, v1, v2, v3};
                    *(float4*)(yout + ((size_t)b * TOUT + t) * 256 + o0) = v;
                    s += v0 + v1 + v2 + v3;
                    q = fmaf(v0, v0, q); q = fmaf(v1, v1, q);
                    q = fmaf(v2, v2, q); q = fmaf(v3, v3, q);
                }
            }
        } else {
            #pragma unroll
            for (int nf = 0; nf < NF; nf++) {
                int t = t0 + nf * 16 + mrow;
                if (t < TOUT) {
                    #pragma unroll
                    for (int r = 0; r < 4; r++) {
                        float v = acc[mf][nf][r] + bias[o0 + r];
                        yout[((size_t)b * 256 + o0 + r) * TOUT + t] = v;
                        s += v; q = fmaf(v, v, q);
                    }
                }
            }
        }
    }
    block_reduce2(s, q, red);
    if (threadIdx.x == 0) {
        int bi = b * 128 + tile * MSC + ms;
        pout[bi * 2]     = s;
        pout[bi * 2 + 1] = q;
    }
}

// D: out[b,0,t] = b3 + sum_o w3[o]*leaky(LN2(y2[b,o,t])). grid (16,4):
// 32 t-lanes x 8 o-chunks of 32, LDS combine.
__global__ void kd_head(const float* __restrict__ y2, const float* __restrict__ p2,
                        const float* __restrict__ g2, const float* __restrict__ bb2,
                        const float* __restrict__ w3, const float* __restrict__ b3,
                        float* __restrict__ out) {
    __shared__ float red[8];
    __shared__ float stat[2];
    __shared__ float part[8][32];
    const int b = blockIdx.y;
    stats_from_partials(p2 + b * 256, 128, 1.f / 128000.f, red, stat);
    const float mean = stat[0], inv = stat[1];
    const int tl = threadIdx.x & 31, fg = threadIdx.x >> 5;
    const int t = blockIdx.x * 32 + tl;
    float acc = 0.f;
    if (t < 500) {
        const float* yb = y2 + ((size_t)b * 256 + fg * 32) * 500 + t;
        #pragma unroll 8
        for (int i = 0; i < 32; i++) {
            int o = fg * 32 + i;
            float raw = yb[(size_t)i * 500];
            float xv = leaky(fmaf(g2[o] * inv, raw - mean, bb2[o]));
            acc = fmaf(w3[o], xv, acc);
        }
    }
    part[fg][tl] = acc;
    __syncthreads();
    if (fg == 0 && t < 500) {
        float r = b3[0];
        #pragma unroll
        for (int i = 0; i < 8; i++) r += part[i][tl];
        out[b * 500 + t] = r;
    }
}

extern "C" void kernel_launch(void* const* d_in, const int* in_sizes, int n_in,
                              void* d_out, int out_size, void* d_ws, size_t ws_size,
                              hipStream_t stream) {
    const float* feature = (const float*)d_in[0];
    const float* mask    = (const float*)d_in[1];
    const float* w2d     = (const float*)d_in[2];
    const float* b2d     = (const float*)d_in[3];
    const float* g2d     = (const float*)d_in[4];
    const float* be2d    = (const float*)d_in[5];
    const float* w1      = (const float*)d_in[6];
    const float* b1      = (const float*)d_in[7];
    const float* g1      = (const float*)d_in[8];
    const float* bb1     = (const float*)d_in[9];
    const float* w2      = (const float*)d_in[10];
    const float* b2      = (const float*)d_in[11];
    const float* g2      = (const float*)d_in[12];
    const float* bb2     = (const float*)d_in[13];
    const float* w3      = (const float*)d_in[14];
    const float* b3      = (const float*)d_in[15];
    float* out = (float*)d_out;

    float* ws = (float*)d_ws;
    float* p0  = ws;                          // 1024
    float* p1  = ws + 1024;                   // 1024
    float* p2  = ws + 2048;                   // 1024
    ushortT* dT = (ushortT*)(ws + 3072);      // [b][2000][128] bf16 = 512,000 floats
    float* y1T = ws + 3072 + 512000;          // [b][1000][256] = 1,024,000
    float* y2  = y1T + 1024000;               // [b][256][500]  = 512,000
    ushortT* w1b = (ushortT*)(y2 + 512000);   // 98,304 ushorts
    ushortT* w2b = w1b + 98304;               // 196,608 ushorts

    // A: inline-a + maskmix + transpose(bf16) + stats0 (+ weight prep).
    ka<<<dim3(63 + 72, 4), 256, 0, stream>>>(feature, mask, w2d, b2d,
                                             w1, w2, w1b, w2b, dT, p0);
    // B: conv1 128->256, T 2000->1000, NT=16, MPB=128, bf16 input, y1T[t][o].
    kconv<128, 2000, 1000, 16, 128, false, true, true>
        <<<dim3(126, 4), 256, 0, stream>>>(
        dT, p0, 63, 1.f / 256000.f, g2d, be2d, w1b, b1, y1T, p1);
    // C: conv2 256->256, T 1000->500, NT=16, MPB=64, fp32 input, y2[o][t].
    kconv<256, 1000, 500, 16, 64, true, false, false>
        <<<dim3(128, 4), 256, 0, stream>>>(
        y1T, p1, 126, 1.f / 256000.f, g1, bb1, w2b, b2, y2, p2);
    // D: final 1x1 conv.
    kd_head<<<dim3(16, 4), 256, 0, stream>>>(y2, p2, g2, bb2, w3, b3, out);
}